// Round 1
// baseline (5780.107 us; speedup 1.0000x reference)
//
#include <hip/hip_runtime.h>
#include <hip/hip_bf16.h>

// GCN: deg/dinv -> t = x@W1 -> agg1(edges) -> h1 = relu(agg1 + d2*t + b1)
//      -> agg2(edges, 16-dim) -> out = (agg2 + d2*h1)@W2 + b2 -> log_softmax
// Aggregation commutes with the linear transform, so layer 2 aggregates in
// 16-dim hidden space (4x fewer atomics than aggregating the 64-dim output).

#define D_IN 512
#define D_HID 16
#define D_OUT 64

__global__ void init_deg_kernel(float* __restrict__ deg, int N) {
    int i = blockIdx.x * blockDim.x + threadIdx.x;
    if (i < N) deg[i] = 1.0f;  // self-loop weight
}

__global__ void deg_kernel(const int* __restrict__ dst, const float* __restrict__ w,
                           float* __restrict__ deg, int E) {
    int e = blockIdx.x * blockDim.x + threadIdx.x;
    if (e < E) unsafeAtomicAdd(&deg[dst[e]], w[e]);
}

__global__ void dinv_kernel(float* __restrict__ deg, int N) {
    int i = blockIdx.x * blockDim.x + threadIdx.x;
    if (i < N) {
        float d = deg[i];
        deg[i] = (d > 0.0f) ? __frsqrt_rn(d) : 0.0f;
    }
}

// t[N][16] = x[N][512] @ W1[512][16]
// Block = 256 threads (4 waves). Each wave handles 4 rows per iteration;
// 16 lanes per row, each lane owns k in {4s+64i : i=0..7} (8 float4 loads,
// coalesced 256B segments). W1^T staged in LDS with pad 520 (2-way banks = free).
__global__ __launch_bounds__(256) void gemm1_kernel(const float* __restrict__ x,
                                                    const float* __restrict__ W1,
                                                    float* __restrict__ t, int N) {
    __shared__ float w1t[16 * 520];
    for (int idx = threadIdx.x; idx < D_IN * D_HID; idx += 256) {
        int k = idx >> 4, j = idx & 15;
        w1t[j * 520 + k] = W1[idx];
    }
    __syncthreads();

    const int wave = threadIdx.x >> 6;
    const int lane = threadIdx.x & 63;
    const int g = lane >> 4;        // row within wave's group of 4
    const int s = lane & 15;        // k-slice owner within row

    for (int base = blockIdx.x * 16; base < N; base += gridDim.x * 16) {
        int row = base + wave * 4 + g;
        if (row < N) {
            const float4* xr = (const float4*)(x + (size_t)row * D_IN);
            float4 xv[8];
#pragma unroll
            for (int i = 0; i < 8; ++i) xv[i] = xr[s + 16 * i];

            float acc[16];
#pragma unroll
            for (int j = 0; j < 16; ++j) acc[j] = 0.0f;

#pragma unroll
            for (int i = 0; i < 8; ++i) {
                int kb = 4 * s + 64 * i;
#pragma unroll
                for (int j = 0; j < 16; ++j) {
                    const float4 wv = *(const float4*)&w1t[j * 520 + kb];
                    acc[j] += xv[i].x * wv.x + xv[i].y * wv.y + xv[i].z * wv.z + xv[i].w * wv.w;
                }
            }
            // reduce across the 16 lanes of this row-group
#pragma unroll
            for (int j = 0; j < 16; ++j) {
#pragma unroll
                for (int m = 1; m < 16; m <<= 1) acc[j] += __shfl_xor(acc[j], m, 64);
            }
            // lane s stores output column s
            float v = acc[0];
#pragma unroll
            for (int j = 1; j < 16; ++j) v = (s == j) ? acc[j] : v;
            t[(size_t)row * 16 + s] = v;
        }
    }
}

// agg[dst] += feat[src] * (dinv[src]*w*dinv[dst]), one edge per thread.
__global__ void agg_kernel(const int* __restrict__ src, const int* __restrict__ dst,
                           const float* __restrict__ w, const float* __restrict__ dinv,
                           const float* __restrict__ feat, float* __restrict__ agg, int E) {
    int e = blockIdx.x * blockDim.x + threadIdx.x;
    if (e >= E) return;
    int s = src[e], d = dst[e];
    float nm = dinv[s] * w[e] * dinv[d];
    const float4* f = (const float4*)(feat + (size_t)s * 16);
    float* o = agg + (size_t)d * 16;
#pragma unroll
    for (int q = 0; q < 4; ++q) {
        float4 v = f[q];
        unsafeAtomicAdd(o + 4 * q + 0, v.x * nm);
        unsafeAtomicAdd(o + 4 * q + 1, v.y * nm);
        unsafeAtomicAdd(o + 4 * q + 2, v.z * nm);
        unsafeAtomicAdd(o + 4 * q + 3, v.w * nm);
    }
}

// h1 = relu(agg1 + dinv^2 * t + b1), written in place over agg1.
__global__ void h1_kernel(float* __restrict__ agg1, const float* __restrict__ t,
                          const float* __restrict__ dinv, const float* __restrict__ b1, int N) {
    int i = blockIdx.x * blockDim.x + threadIdx.x;   // float4 index, N*4 total
    if (i >= N * 4) return;
    int node = i >> 2;
    float di = dinv[node];
    float d2 = di * di;
    float4 a = ((const float4*)agg1)[i];
    float4 tv = ((const float4*)t)[i];
    float4 b = ((const float4*)b1)[i & 3];
    float4 r;
    r.x = fmaxf(a.x + d2 * tv.x + b.x, 0.0f);
    r.y = fmaxf(a.y + d2 * tv.y + b.y, 0.0f);
    r.z = fmaxf(a.z + d2 * tv.z + b.z, 0.0f);
    r.w = fmaxf(a.w + d2 * tv.w + b.w, 0.0f);
    ((float4*)agg1)[i] = r;
}

// out[node][j] = log_softmax( (agg2[node] + d2*h1[node]) @ W2 + b2 )
// One wave per node: lane j in 0..63 owns output column j.
__global__ __launch_bounds__(256) void out_kernel(const float* __restrict__ agg2,
                                                  const float* __restrict__ h1,
                                                  const float* __restrict__ dinv,
                                                  const float* __restrict__ W2,
                                                  const float* __restrict__ b2,
                                                  float* __restrict__ out, int N) {
    __shared__ float w2s[16 * 64];
    __shared__ float b2s[64];
    for (int idx = threadIdx.x; idx < 16 * 64; idx += 256) w2s[idx] = W2[idx];
    if (threadIdx.x < 64) b2s[threadIdx.x] = b2[threadIdx.x];
    __syncthreads();

    const int wave = threadIdx.x >> 6;
    const int lane = threadIdx.x & 63;

    for (int node = blockIdx.x * 4 + wave; node < N; node += gridDim.x * 4) {
        float di = dinv[node];
        float d2 = di * di;
        const float4* a4 = (const float4*)(agg2 + (size_t)node * 16);
        const float4* h4 = (const float4*)(h1 + (size_t)node * 16);
        float z = b2s[lane];
#pragma unroll
        for (int q = 0; q < 4; ++q) {
            float4 a = a4[q], h = h4[q];
            float v0 = a.x + d2 * h.x;
            float v1 = a.y + d2 * h.y;
            float v2 = a.z + d2 * h.z;
            float v3 = a.w + d2 * h.w;
            z += v0 * w2s[(4 * q + 0) * 64 + lane];
            z += v1 * w2s[(4 * q + 1) * 64 + lane];
            z += v2 * w2s[(4 * q + 2) * 64 + lane];
            z += v3 * w2s[(4 * q + 3) * 64 + lane];
        }
        float m = z;
#pragma unroll
        for (int off = 32; off; off >>= 1) m = fmaxf(m, __shfl_xor(m, off, 64));
        float ez = __expf(z - m);
        float ssum = ez;
#pragma unroll
        for (int off = 32; off; off >>= 1) ssum += __shfl_xor(ssum, off, 64);
        out[(size_t)node * 64 + lane] = z - m - __logf(ssum);
    }
}

extern "C" void kernel_launch(void* const* d_in, const int* in_sizes, int n_in,
                              void* d_out, int out_size, void* d_ws, size_t ws_size,
                              hipStream_t stream) {
    const float* x  = (const float*)d_in[0];
    const int*   ei = (const int*)d_in[1];
    const float* ew = (const float*)d_in[2];
    const float* W1 = (const float*)d_in[3];
    const float* b1 = (const float*)d_in[4];
    const float* W2 = (const float*)d_in[5];
    const float* b2 = (const float*)d_in[6];
    float* out = (float*)d_out;

    const int N = in_sizes[0] / D_IN;
    const int E = in_sizes[2];
    const int* srcI = ei;
    const int* dstI = ei + E;

    // ws layout (floats): deg/dinv [N] | t [16N] (reused as agg2) | agg1/h1 [16N]
    float* ws   = (float*)d_ws;
    float* deg  = ws;                       // becomes dinv after dinv_kernel
    float* t    = ws + N;                   // reused as agg2 after h1 is built
    float* agg1 = ws + (size_t)N * 17;      // becomes h1 in place
    float* agg2 = t;
    float* h1   = agg1;

    hipMemsetAsync(agg1, 0, (size_t)N * 16 * sizeof(float), stream);

    init_deg_kernel<<<(N + 255) / 256, 256, 0, stream>>>(deg, N);
    deg_kernel<<<(E + 255) / 256, 256, 0, stream>>>(dstI, ew, deg, E);
    dinv_kernel<<<(N + 255) / 256, 256, 0, stream>>>(deg, N);

    gemm1_kernel<<<1024, 256, 0, stream>>>(x, W1, t, N);
    agg_kernel<<<(E + 255) / 256, 256, 0, stream>>>(srcI, dstI, ew, deg, t, agg1, E);
    h1_kernel<<<(N * 4 + 255) / 256, 256, 0, stream>>>(agg1, t, deg, b1, N);

    // t is dead now; reuse as agg2
    hipMemsetAsync(agg2, 0, (size_t)N * 16 * sizeof(float), stream);
    agg_kernel<<<(E + 255) / 256, 256, 0, stream>>>(srcI, dstI, ew, deg, h1, agg2, E);

    out_kernel<<<2048, 256, 0, stream>>>(agg2, h1, deg, W2, b2, out, N);
}

// Round 2
// 1114.207 us; speedup vs baseline: 5.1876x; 5.1876x over previous
//
#include <hip/hip_runtime.h>
#include <hip/hip_bf16.h>

// GCN via CSR counting-sort (built once, reused by both layers):
//   deg/hist -> dinv -> scan -> scatter(src,norm) -> t = x@W1
//   -> agg1 CSR (fused +d2*t+b1, relu) = h1
//   -> agg2 CSR (fused +d2*h1) = v -> out = v@W2+b2 -> log_softmax
// No scattered f32 atomics anywhere: round-1 profile showed 51.2M edge
// atomics thrashing HBM (1.6 GB WRITE_SIZE, 2640 us per agg dispatch).

#define D_IN 512
#define D_HID 16
#define D_OUT 64

__global__ void init_kernel(float* __restrict__ deg, int* __restrict__ cnt, int N) {
    int i = blockIdx.x * blockDim.x + threadIdx.x;
    if (i < N) { deg[i] = 1.0f; cnt[i] = 0; }  // self-loop weight 1
}

__global__ void deg_hist_kernel(const int* __restrict__ dst, const float* __restrict__ w,
                                float* __restrict__ deg, int* __restrict__ cnt, int E) {
    int e = blockIdx.x * blockDim.x + threadIdx.x;
    if (e < E) {
        int d = dst[e];
        unsafeAtomicAdd(&deg[d], w[e]);
        atomicAdd(&cnt[d], 1);
    }
}

__global__ void dinv_kernel(float* __restrict__ deg, int N) {
    int i = blockIdx.x * blockDim.x + threadIdx.x;
    if (i < N) {
        float d = deg[i];
        deg[i] = (d > 0.0f) ? __frsqrt_rn(d) : 0.0f;
    }
}

// Single-block chunked exclusive scan over cnt[N] -> row_start[N+1], cursor[N].
__global__ __launch_bounds__(1024) void scan_kernel(const int* __restrict__ cnt,
                                                    int* __restrict__ row_start,
                                                    int* __restrict__ cursor, int N) {
    __shared__ int sums[1024];
    const int tid = threadIdx.x;
    const int chunk = (N + 1023) >> 10;
    const int beg = tid * chunk;
    const int end = min(beg + chunk, N);
    int s = 0;
    for (int i = beg; i < end; ++i) s += cnt[i];
    sums[tid] = s;
    __syncthreads();
    for (int off = 1; off < 1024; off <<= 1) {  // inclusive Hillis-Steele
        int v = (tid >= off) ? sums[tid - off] : 0;
        __syncthreads();
        sums[tid] += v;
        __syncthreads();
    }
    int running = (tid == 0) ? 0 : sums[tid - 1];
    for (int i = beg; i < end; ++i) {
        int c = cnt[i];
        row_start[i] = running;
        cursor[i] = running;
        running += c;
    }
    if (tid == 1023) row_start[N] = sums[1023];
}

__global__ void scatter_kernel(const int* __restrict__ src, const int* __restrict__ dst,
                               const float* __restrict__ w, const float* __restrict__ dinv,
                               int* __restrict__ cursor, float2* __restrict__ sorted, int E) {
    int e = blockIdx.x * blockDim.x + threadIdx.x;
    if (e >= E) return;
    int s = src[e], d = dst[e];
    float nm = dinv[s] * w[e] * dinv[d];
    int pos = atomicAdd(&cursor[d], 1);
    sorted[pos] = make_float2(__int_as_float(s), nm);
}

// t[N][16] = x[N][512] @ W1[512][16]; 16 lanes/row, each owns 8 float4 k-slices.
__global__ __launch_bounds__(256) void gemm1_kernel(const float* __restrict__ x,
                                                    const float* __restrict__ W1,
                                                    float* __restrict__ t, int N) {
    __shared__ float w1t[16 * 520];
    for (int idx = threadIdx.x; idx < D_IN * D_HID; idx += 256) {
        int k = idx >> 4, j = idx & 15;
        w1t[j * 520 + k] = W1[idx];
    }
    __syncthreads();

    const int wave = threadIdx.x >> 6;
    const int lane = threadIdx.x & 63;
    const int g = lane >> 4;
    const int s = lane & 15;

    for (int base = blockIdx.x * 16; base < N; base += gridDim.x * 16) {
        int row = base + wave * 4 + g;
        if (row < N) {
            const float4* xr = (const float4*)(x + (size_t)row * D_IN);
            float4 xv[8];
#pragma unroll
            for (int i = 0; i < 8; ++i) xv[i] = xr[s + 16 * i];
            float acc[16];
#pragma unroll
            for (int j = 0; j < 16; ++j) acc[j] = 0.0f;
#pragma unroll
            for (int i = 0; i < 8; ++i) {
                int kb = 4 * s + 64 * i;
#pragma unroll
                for (int j = 0; j < 16; ++j) {
                    const float4 wv = *(const float4*)&w1t[j * 520 + kb];
                    acc[j] += xv[i].x * wv.x + xv[i].y * wv.y + xv[i].z * wv.z + xv[i].w * wv.w;
                }
            }
#pragma unroll
            for (int j = 0; j < 16; ++j) {
#pragma unroll
                for (int m = 1; m < 16; m <<= 1) acc[j] += __shfl_xor(acc[j], m, 64);
            }
            float v = acc[0];
#pragma unroll
            for (int j = 1; j < 16; ++j) v = (s == j) ? acc[j] : v;
            t[(size_t)row * 16 + s] = v;
        }
    }
}

// CSR aggregation: 16 lanes per node (lane j = feature dim j), no atomics.
// LAYER 1: out = relu(acc + d2*selfv + b1[j]);  LAYER 2: out = acc + d2*selfv.
template <int LAYER>
__global__ __launch_bounds__(256) void agg_csr_kernel(const float2* __restrict__ sorted,
                                                      const int* __restrict__ row_start,
                                                      const float* __restrict__ feat,
                                                      const float* __restrict__ selfv,
                                                      const float* __restrict__ dinv,
                                                      const float* __restrict__ b1,
                                                      float* __restrict__ out, int N) {
    const int node = blockIdx.x * 16 + (threadIdx.x >> 4);
    const int j = threadIdx.x & 15;
    if (node >= N) return;
    const int beg = row_start[node];
    const int end = row_start[node + 1];
    float acc = 0.0f, acc2 = 0.0f;
    int e = beg;
    for (; e + 2 <= end; e += 2) {
        float2 p0 = sorted[e];
        float2 p1 = sorted[e + 1];
        acc  += p0.y * feat[(size_t)__float_as_int(p0.x) * 16 + j];
        acc2 += p1.y * feat[(size_t)__float_as_int(p1.x) * 16 + j];
    }
    if (e < end) {
        float2 p = sorted[e];
        acc += p.y * feat[(size_t)__float_as_int(p.x) * 16 + j];
    }
    acc += acc2;
    float di = dinv[node];
    float d2 = di * di;
    float sv = selfv[(size_t)node * 16 + j];
    if (LAYER == 1) {
        out[(size_t)node * 16 + j] = fmaxf(acc + d2 * sv + b1[j], 0.0f);
    } else {
        out[(size_t)node * 16 + j] = acc + d2 * sv;
    }
}

// out[node][c] = log_softmax( v[node] @ W2 + b2 ); one wave per node.
__global__ __launch_bounds__(256) void out_kernel(const float* __restrict__ v,
                                                  const float* __restrict__ W2,
                                                  const float* __restrict__ b2,
                                                  float* __restrict__ out, int N) {
    __shared__ float w2s[16 * 64];
    __shared__ float b2s[64];
    for (int idx = threadIdx.x; idx < 16 * 64; idx += 256) w2s[idx] = W2[idx];
    if (threadIdx.x < 64) b2s[threadIdx.x] = b2[threadIdx.x];
    __syncthreads();

    const int wave = threadIdx.x >> 6;
    const int lane = threadIdx.x & 63;

    for (int node = blockIdx.x * 4 + wave; node < N; node += gridDim.x * 4) {
        const float4* v4 = (const float4*)(v + (size_t)node * 16);
        float z = b2s[lane];
#pragma unroll
        for (int q = 0; q < 4; ++q) {
            float4 a = v4[q];
            z += a.x * w2s[(4 * q + 0) * 64 + lane];
            z += a.y * w2s[(4 * q + 1) * 64 + lane];
            z += a.z * w2s[(4 * q + 2) * 64 + lane];
            z += a.w * w2s[(4 * q + 3) * 64 + lane];
        }
        float m = z;
#pragma unroll
        for (int off = 32; off; off >>= 1) m = fmaxf(m, __shfl_xor(m, off, 64));
        float ez = __expf(z - m);
        float ssum = ez;
#pragma unroll
        for (int off = 32; off; off >>= 1) ssum += __shfl_xor(ssum, off, 64);
        out[(size_t)node * 64 + lane] = z - m - __logf(ssum);
    }
}

extern "C" void kernel_launch(void* const* d_in, const int* in_sizes, int n_in,
                              void* d_out, int out_size, void* d_ws, size_t ws_size,
                              hipStream_t stream) {
    const float* x  = (const float*)d_in[0];
    const int*   ei = (const int*)d_in[1];
    const float* ew = (const float*)d_in[2];
    const float* W1 = (const float*)d_in[3];
    const float* b1 = (const float*)d_in[4];
    const float* W2 = (const float*)d_in[5];
    const float* b2 = (const float*)d_in[6];
    float* out = (float*)d_out;

    const int N = in_sizes[0] / D_IN;
    const int E = in_sizes[2];
    const int* srcI = ei;
    const int* dstI = ei + E;

    // ws layout (float units): dinv[N] cnt[N] row_start[N+1] pad cursor[N]
    //                          t/v[16N] h1[16N] sorted[2E]
    float* ws = (float*)d_ws;
    float* dinv      = ws;
    int*   cnt       = (int*)(ws + N);
    int*   row_start = (int*)(ws + 2 * (size_t)N);
    int*   cursor    = (int*)(ws + 3 * (size_t)N + 2);
    float* t         = ws + 4 * (size_t)N + 2;   // reused as v after agg2
    float* h1        = ws + 20 * (size_t)N + 2;
    float2* sorted   = (float2*)(ws + 36 * (size_t)N + 2);
    float* v = t;

    init_kernel<<<(N + 255) / 256, 256, 0, stream>>>(dinv, cnt, N);
    deg_hist_kernel<<<(E + 255) / 256, 256, 0, stream>>>(dstI, ew, dinv, cnt, E);
    dinv_kernel<<<(N + 255) / 256, 256, 0, stream>>>(dinv, N);
    scan_kernel<<<1, 1024, 0, stream>>>(cnt, row_start, cursor, N);
    scatter_kernel<<<(E + 255) / 256, 256, 0, stream>>>(srcI, dstI, ew, dinv, cursor, sorted, E);

    gemm1_kernel<<<1024, 256, 0, stream>>>(x, W1, t, N);

    agg_csr_kernel<1><<<(N + 15) / 16, 256, 0, stream>>>(sorted, row_start, t, t, dinv, b1, h1, N);
    agg_csr_kernel<2><<<(N + 15) / 16, 256, 0, stream>>>(sorted, row_start, h1, h1, dinv, b1, v, N);

    out_kernel<<<2048, 256, 0, stream>>>(v, W2, b2, out, N);
}

// Round 3
// 918.815 us; speedup vs baseline: 6.2908x; 1.2127x over previous
//
#include <hip/hip_runtime.h>
#include <hip/hip_bf16.h>

// GCN via CSR counting-sort. Round-3 changes vs round-2:
//  - histogram uses per-XCD count tables + workgroup-scope (L2-local) atomics
//    (device-scope atomics are memory-side: ~20G/s, 32B HBM write each)
//  - deg is computed from the CSR (no float atomics); scatter stores (src,w)
//    and norm = dinv[s]*w*dinv[d] is applied inside the agg kernels
//  - 3-stage parallel scan instead of single-block scan
//  - agg: one wave per node, 4-way edge ILP

#define D_IN 512
#define D_HID 16
#define D_OUT 64
#define NB 256   // scan blocks
#define BT 256   // threads per block

__device__ __forceinline__ int xcc_id() {
    int id;
    asm volatile("s_getreg_b32 %0, hwreg(HW_REG_XCC_ID)" : "=s"(id));
    return id & 7;
}

// cnt8[x][d]++ with XCD-local L2 atomics.
__global__ void hist_kernel(const int* __restrict__ dst, int* __restrict__ cnt8, int N, int E) {
    int e = blockIdx.x * blockDim.x + threadIdx.x;
    if (e >= E) return;
    int x = xcc_id();
    __hip_atomic_fetch_add(&cnt8[(size_t)x * N + dst[e]], 1,
                           __ATOMIC_RELAXED, __HIP_MEMORY_SCOPE_WORKGROUP);
}

// cnt_tot[n] = sum_x cnt8[x][n]; bsum[b] = sum over block's node chunk.
__global__ __launch_bounds__(BT) void scanA_kernel(const int* __restrict__ cnt8,
                                                   int* __restrict__ cnt_tot,
                                                   int* __restrict__ bsum, int N) {
    __shared__ int red[BT / 64];
    int b = blockIdx.x;
    int chunk = (N + NB - 1) / NB;
    int beg = b * chunk, end = min(beg + chunk, N);
    int local = 0;
    for (int n = beg + threadIdx.x; n < end; n += BT) {
        int t = 0;
#pragma unroll
        for (int x = 0; x < 8; ++x) t += cnt8[(size_t)x * N + n];
        cnt_tot[n] = t;
        local += t;
    }
#pragma unroll
    for (int off = 32; off; off >>= 1) local += __shfl_down(local, off, 64);
    if ((threadIdx.x & 63) == 0) red[threadIdx.x >> 6] = local;
    __syncthreads();
    if (threadIdx.x == 0) {
        int s = 0;
#pragma unroll
        for (int i = 0; i < BT / 64; ++i) s += red[i];
        bsum[b] = s;
    }
}

// exclusive scan of bsum[NB] -> bbase[NB]
__global__ __launch_bounds__(NB) void scanB_kernel(const int* __restrict__ bsum,
                                                   int* __restrict__ bbase) {
    __shared__ int s[NB];
    int t = threadIdx.x;
    int orig = bsum[t];
    s[t] = orig;
    __syncthreads();
    for (int off = 1; off < NB; off <<= 1) {
        int v = (t >= off) ? s[t - off] : 0;
        __syncthreads();
        s[t] += v;
        __syncthreads();
    }
    bbase[t] = s[t] - orig;
}

// row_start[n] + cursor[n] from cnt_tot and bbase.
__global__ __launch_bounds__(BT) void scanC_kernel(const int* __restrict__ cnt_tot,
                                                   const int* __restrict__ bbase,
                                                   int* __restrict__ row_start,
                                                   int* __restrict__ cursor, int N, int E) {
    __shared__ int ex[BT];
    int b = blockIdx.x;
    int chunk = (N + NB - 1) / NB;
    int per = (chunk + BT - 1) / BT;
    int beg = b * chunk, end = min(beg + chunk, N);
    int tbeg = min(beg + threadIdx.x * per, end);
    int tend = min(tbeg + per, end);
    int s = 0;
    for (int n = tbeg; n < tend; ++n) s += cnt_tot[n];
    int orig = s;
    int t = threadIdx.x;
    ex[t] = s;
    __syncthreads();
    for (int off = 1; off < BT; off <<= 1) {
        int v = (t >= off) ? ex[t - off] : 0;
        __syncthreads();
        ex[t] += v;
        __syncthreads();
    }
    int running = bbase[b] + ex[t] - orig;
    for (int n = tbeg; n < tend; ++n) {
        row_start[n] = running;
        cursor[n] = running;
        running += cnt_tot[n];
    }
    if (b == 0 && t == 0) row_start[N] = E;
}

__global__ void scatter_kernel(const int* __restrict__ src, const int* __restrict__ dst,
                               const float* __restrict__ w, int* __restrict__ cursor,
                               float2* __restrict__ sorted, int E) {
    int e = blockIdx.x * blockDim.x + threadIdx.x;
    if (e >= E) return;
    int pos = atomicAdd(&cursor[dst[e]], 1);
    sorted[pos] = make_float2(__int_as_float(src[e]), w[e]);
}

// dinv[n] = rsqrt(1 + sum of w over CSR row). One wave per node.
__global__ __launch_bounds__(256) void dinv_kernel(const float2* __restrict__ sorted,
                                                   const int* __restrict__ row_start,
                                                   float* __restrict__ dinv, int N) {
    int node = blockIdx.x * 4 + (threadIdx.x >> 6);
    if (node >= N) return;
    int lane = threadIdx.x & 63;
    int beg = row_start[node], end = row_start[node + 1];
    float s = 0.0f;
    for (int e = beg + lane; e < end; e += 64) s += sorted[e].y;
#pragma unroll
    for (int off = 32; off; off >>= 1) s += __shfl_xor(s, off, 64);
    if (lane == 0) dinv[node] = __frsqrt_rn(1.0f + s);
}

// t[N][16] = x[N][512] @ W1[512][16]; 16 lanes/row, each owns 8 float4 k-slices.
__global__ __launch_bounds__(256) void gemm1_kernel(const float* __restrict__ x,
                                                    const float* __restrict__ W1,
                                                    float* __restrict__ t, int N) {
    __shared__ float w1t[16 * 520];
    for (int idx = threadIdx.x; idx < D_IN * D_HID; idx += 256) {
        int k = idx >> 4, j = idx & 15;
        w1t[j * 520 + k] = W1[idx];
    }
    __syncthreads();

    const int wave = threadIdx.x >> 6;
    const int lane = threadIdx.x & 63;
    const int g = lane >> 4;
    const int s = lane & 15;

    for (int base = blockIdx.x * 16; base < N; base += gridDim.x * 16) {
        int row = base + wave * 4 + g;
        if (row < N) {
            const float4* xr = (const float4*)(x + (size_t)row * D_IN);
            float4 xv[8];
#pragma unroll
            for (int i = 0; i < 8; ++i) xv[i] = xr[s + 16 * i];
            float acc[16];
#pragma unroll
            for (int j = 0; j < 16; ++j) acc[j] = 0.0f;
#pragma unroll
            for (int i = 0; i < 8; ++i) {
                int kb = 4 * s + 64 * i;
#pragma unroll
                for (int j = 0; j < 16; ++j) {
                    const float4 wv = *(const float4*)&w1t[j * 520 + kb];
                    acc[j] += xv[i].x * wv.x + xv[i].y * wv.y + xv[i].z * wv.z + xv[i].w * wv.w;
                }
            }
#pragma unroll
            for (int j = 0; j < 16; ++j) {
#pragma unroll
                for (int m = 1; m < 16; m <<= 1) acc[j] += __shfl_xor(acc[j], m, 64);
            }
            float v = acc[0];
#pragma unroll
            for (int j = 1; j < 16; ++j) v = (s == j) ? acc[j] : v;
            t[(size_t)row * 16 + s] = v;
        }
    }
}

// One wave per node, lane = k*16 + j (k = edge slice, j = feature dim).
// acc_j = sum over row of dinv[s]*w*feat[s][j]; out = dinv[n]*acc + dinv[n]^2*selfv.
template <int LAYER>
__global__ __launch_bounds__(256) void agg_kernel(const float2* __restrict__ sorted,
                                                  const int* __restrict__ row_start,
                                                  const float* __restrict__ feat,
                                                  const float* __restrict__ selfv,
                                                  const float* __restrict__ dinv,
                                                  const float* __restrict__ b1,
                                                  float* __restrict__ outp, int N) {
    int node = blockIdx.x * 4 + (threadIdx.x >> 6);
    if (node >= N) return;
    int lane = threadIdx.x & 63;
    int j = lane & 15, k = lane >> 4;
    int beg = row_start[node], end = row_start[node + 1];
    float acc = 0.0f;
    for (int e = beg + k; e < end; e += 4) {
        float2 p = sorted[e];
        int s = __float_as_int(p.x);
        acc += dinv[s] * p.y * feat[(size_t)s * 16 + j];
    }
    acc += __shfl_xor(acc, 16, 64);
    acc += __shfl_xor(acc, 32, 64);
    float dn = dinv[node];
    float sv = selfv[(size_t)node * 16 + j];
    float r = dn * acc + dn * dn * sv;
    if (LAYER == 1) r = fmaxf(r + b1[j], 0.0f);
    if (k == 0) outp[(size_t)node * 16 + j] = r;
}

// out[node][c] = log_softmax( v[node] @ W2 + b2 ); one wave per node.
__global__ __launch_bounds__(256) void out_kernel(const float* __restrict__ v,
                                                  const float* __restrict__ W2,
                                                  const float* __restrict__ b2,
                                                  float* __restrict__ out, int N) {
    __shared__ float w2s[16 * 64];
    __shared__ float b2s[64];
    for (int idx = threadIdx.x; idx < 16 * 64; idx += 256) w2s[idx] = W2[idx];
    if (threadIdx.x < 64) b2s[threadIdx.x] = b2[threadIdx.x];
    __syncthreads();

    const int wave = threadIdx.x >> 6;
    const int lane = threadIdx.x & 63;

    for (int node = blockIdx.x * 4 + wave; node < N; node += gridDim.x * 4) {
        const float4* v4 = (const float4*)(v + (size_t)node * 16);
        float z = b2s[lane];
#pragma unroll
        for (int q = 0; q < 4; ++q) {
            float4 a = v4[q];
            z += a.x * w2s[(4 * q + 0) * 64 + lane];
            z += a.y * w2s[(4 * q + 1) * 64 + lane];
            z += a.z * w2s[(4 * q + 2) * 64 + lane];
            z += a.w * w2s[(4 * q + 3) * 64 + lane];
        }
        float m = z;
#pragma unroll
        for (int off = 32; off; off >>= 1) m = fmaxf(m, __shfl_xor(m, off, 64));
        float ez = __expf(z - m);
        float ssum = ez;
#pragma unroll
        for (int off = 32; off; off >>= 1) ssum += __shfl_xor(ssum, off, 64);
        out[(size_t)node * 64 + lane] = z - m - __logf(ssum);
    }
}

extern "C" void kernel_launch(void* const* d_in, const int* in_sizes, int n_in,
                              void* d_out, int out_size, void* d_ws, size_t ws_size,
                              hipStream_t stream) {
    const float* x  = (const float*)d_in[0];
    const int*   ei = (const int*)d_in[1];
    const float* ew = (const float*)d_in[2];
    const float* W1 = (const float*)d_in[3];
    const float* b1 = (const float*)d_in[4];
    const float* W2 = (const float*)d_in[5];
    const float* b2 = (const float*)d_in[6];
    float* out = (float*)d_out;

    const int N = in_sizes[0] / D_IN;
    const int E = in_sizes[2];
    const int* srcI = ei;
    const int* dstI = ei + E;

    // ws layout (float units):
    // dinv[N] cnt_tot[N] row_start[N+2] cursor[N] bsum[256] bbase[256]
    // cnt8[8N] t[16N] h1[16N] sorted[2E]
    float* ws = (float*)d_ws;
    float* dinv      = ws;
    int*   cnt_tot   = (int*)(ws + (size_t)N);
    int*   row_start = (int*)(ws + 2 * (size_t)N);
    int*   cursor    = (int*)(ws + 3 * (size_t)N + 2);
    int*   bsum      = (int*)(ws + 4 * (size_t)N + 2);
    int*   bbase     = (int*)(ws + 4 * (size_t)N + 258);
    int*   cnt8      = (int*)(ws + 4 * (size_t)N + 514);
    float* t         = ws + 12 * (size_t)N + 514;
    float* h1        = ws + 28 * (size_t)N + 514;
    float2* sorted   = (float2*)(ws + 44 * (size_t)N + 514);
    float* v = t;  // reuse t as layer-2 aggregate

    hipMemsetAsync(cnt8, 0, (size_t)8 * N * sizeof(int), stream);

    hist_kernel<<<(E + 255) / 256, 256, 0, stream>>>(dstI, cnt8, N, E);
    scanA_kernel<<<NB, BT, 0, stream>>>(cnt8, cnt_tot, bsum, N);
    scanB_kernel<<<1, NB, 0, stream>>>(bsum, bbase);
    scanC_kernel<<<NB, BT, 0, stream>>>(cnt_tot, bbase, row_start, cursor, N, E);
    scatter_kernel<<<(E + 255) / 256, 256, 0, stream>>>(srcI, dstI, ew, cursor, sorted, E);
    dinv_kernel<<<(N + 3) / 4, 256, 0, stream>>>(sorted, row_start, dinv, N);

    gemm1_kernel<<<1024, 256, 0, stream>>>(x, W1, t, N);

    agg_kernel<1><<<(N + 3) / 4, 256, 0, stream>>>(sorted, row_start, t, t, dinv, b1, h1, N);
    agg_kernel<2><<<(N + 3) / 4, 256, 0, stream>>>(sorted, row_start, h1, h1, dinv, b1, v, N);

    out_kernel<<<2048, 256, 0, stream>>>(v, W2, b2, out, N);
}